// Round 7
// baseline (360.389 us; speedup 1.0000x reference)
//
#include <hip/hip_runtime.h>

// Orient_Conv: 3x3 orientation-gated conv, 4 orientations + per-pixel argmax.
// B=4, CIN=COUT=32, H=W=128, pad=1.
//
// Gate identity (C=cos(wr), S=sin(wr), r0=cos(th), r1=sin(th)):
//   u = C*r0+S*r1, v = C*r1-S*r0
//   gates: o0=relu(u), o1=relu(v), o2=relu(-u)=relu(u)-u, o3=relu(v)-v
// Rotated weights at tap (i,j): w0=w[i][j], w1=w[2-j][i], w2=w[2-i][2-j],
//   w3=w[j][2-i].
//
// R6 = R5 inner loop, occupancy-restructured: block 256 (32oc x 8pxg, 4px/thr)
// grid 2048 -> 8 blocks/CU (R5: 512-thr blocks, 4/CU, 41% occupancy, 28% VALU
// idle). Single merged LDS array (imm-offset ds_reads) + weight table
// re-laid as [cc][oc][tap][8] so all 18 weight loads/channel use imm offsets
// from one base. Scalar fp32 core: 16 VALU ops/elem = 123 us floor.

#define B_    4
#define CIN_  32
#define COUT_ 32
#define H_    128
#define W_    128
#define HW_   (H_ * W_)
#define OUTSZ_ (B_ * COUT_ * H_ * W_)

// tab layout: [cc][oc][tap][8] = {C,S,w0,w1,w2,w3,0,0}; 32*32*9*8 = 294912 B
__global__ __launch_bounds__(256)
void build_wtab(const float* __restrict__ w, const float* __restrict__ wr,
                float* __restrict__ tab)
{
    int idx = blockIdx.x * 256 + threadIdx.x;   // ((cc*32+oc)*9+tap)
    if (idx >= CIN_ * COUT_ * 9) return;        // 9216
    int tap = idx % 9;
    int t2  = idx / 9;
    int oc  = t2 & 31;
    int cc  = t2 >> 5;
    int i = tap / 3, j = tap - i * 3;
    int base = (oc * CIN_ + cc) * 9;
    float w0 = w[base + i * 3 + j];
    float w1 = w[base + (2 - j) * 3 + i];
    float w2 = w[base + (2 - i) * 3 + (2 - j)];
    float w3 = w[base + j * 3 + (2 - i)];
    float S, C;
    sincosf(wr[base + i * 3 + j], &S, &C);
    float* dst = tab + (size_t)idx * 8;
    dst[0] = C;  dst[1] = S;
    dst[2] = w0; dst[3] = w1;
    dst[4] = w2; dst[5] = w3;
    dst[6] = 0.0f; dst[7] = 0.0f;
}

#define NC_    8                      // channels staged per barrier-pair
#define NG_    (CIN_ / NC_)           // 4 groups
#define CSTR_  36                     // padded col stride (34 used)
#define CLSTR_ (3 * CSTR_)            // 108 floats per (cl)
#define ASTR_  (NC_ * CLSTR_)         // 864 floats per array
#define USED_  (NC_ * 3 * 34)         // 816 used slots per array

__global__ __launch_bounds__(256, 4)
void orient_conv_kernel(const float* __restrict__ f,
                        const float* __restrict__ r0,
                        const float* __restrict__ r1,
                        const float* __restrict__ tab,
                        float* __restrict__ out)
{
    // one array: [arr(3)][cl(8)][row(3)][col(36)]; arr: 0=f, 1=r0, 2=r1
    __shared__ float sm[3 * ASTR_];    // 2592 floats = 10368 B

    const int tid   = threadIdx.x;
    const int oc    = tid & 31;
    const int pxg   = tid >> 5;            // 0..7
    const int px0   = pxg << 2;            // 4 px per thread
    const int bid   = blockIdx.x;          // 0..2047
    const int b     = bid >> 9;
    const int rem   = bid & 511;
    const int h     = rem >> 2;
    const int wbase = (rem & 3) << 5;      // 0,32,64,96

    // ---- staging descriptors: 4 rounds (slot = tid + 256k, valid < 816) ----
    int      goff[4], sidx[4];
    unsigned msk[4];
#pragma unroll
    for (int k = 0; k < 4; ++k) {
        int s = tid + (k << 8);
        if (s < USED_) {
            int cl  = s / 102;            // 3*34 = 102 slots per cl
            int r2  = s - cl * 102;
            int row = r2 / 34;
            int col = r2 - row * 34;
            int gh = h + row - 1;
            int gw = wbase + col - 1;
            bool ok = ((unsigned)gh < (unsigned)H_) & ((unsigned)gw < (unsigned)W_);
            goff[k] = ok ? (cl * HW_ + gh * W_ + gw) : 0;
            msk[k]  = ok ? 0xFFFFFFFFu : 0u;
            sidx[k] = cl * CLSTR_ + row * CSTR_ + col;
        } else { goff[k] = 0; msk[k] = 0u; sidx[k] = ASTR_ - 1; }
    }
    const bool have3 = (tid + 768) < USED_;   // tid < 48
    const int chanBase = b * (CIN_ * HW_);

    float acc[4][4];                       // [px][orient]
#pragma unroll
    for (int p = 0; p < 4; ++p)
#pragma unroll
        for (int o = 0; o < 4; ++o) acc[p][o] = 0.0f;

    // ---- prefetch group 0 ----
    float tF[4], tA[4], tB[4];
    {
        const float* fb = f  + chanBase;
        const float* ab = r0 + chanBase;
        const float* bb = r1 + chanBase;
#pragma unroll
        for (int k = 0; k < 3; ++k) {
            tF[k] = fb[goff[k]]; tA[k] = ab[goff[k]]; tB[k] = bb[goff[k]];
        }
        if (have3) { tF[3] = fb[goff[3]]; tA[3] = ab[goff[3]]; tB[3] = bb[goff[3]]; }
    }

#pragma unroll 1
    for (int g = 0; g < NG_; ++g) {
        __syncthreads();   // all waves done reading LDS of group g-1
#pragma unroll
        for (int k = 0; k < 3; ++k) {
            sm[            sidx[k]] = __uint_as_float(__float_as_uint(tF[k]) & msk[k]);
            sm[ASTR_     + sidx[k]] = __uint_as_float(__float_as_uint(tA[k]) & msk[k]);
            sm[2 * ASTR_ + sidx[k]] = __uint_as_float(__float_as_uint(tB[k]) & msk[k]);
        }
        if (have3) {
            sm[            sidx[3]] = __uint_as_float(__float_as_uint(tF[3]) & msk[3]);
            sm[ASTR_     + sidx[3]] = __uint_as_float(__float_as_uint(tA[3]) & msk[3]);
            sm[2 * ASTR_ + sidx[3]] = __uint_as_float(__float_as_uint(tB[3]) & msk[3]);
        }
        __syncthreads();

        // ---- prefetch group g+1 (in flight during compute below) ----
        if (g + 1 < NG_) {
            const int gb = chanBase + (g + 1) * (NC_ * HW_);
            const float* fb = f  + gb;
            const float* ab = r0 + gb;
            const float* bb = r1 + gb;
#pragma unroll
            for (int k = 0; k < 3; ++k) {
                tF[k] = fb[goff[k]]; tA[k] = ab[goff[k]]; tB[k] = bb[goff[k]];
            }
            if (have3) { tF[3] = fb[goff[3]]; tA[3] = ab[goff[3]]; tB[3] = bb[goff[3]]; }
        }

        // ---- compute the NC_ staged channels ----
#pragma unroll 1
        for (int cl = 0; cl < NC_; ++cl) {
            const int cc = g * NC_ + cl;
            const float* wcc = tab + (size_t)((cc << 5) | oc) * 72;  // 288 B
#pragma unroll
            for (int i = 0; i < 3; ++i) {
                const int bi = cl * CLSTR_ + i * CSTR_ + px0;
                float4 F4 = *reinterpret_cast<const float4*>(&sm[bi]);
                float2 F2 = *reinterpret_cast<const float2*>(&sm[bi + 4]);
                float4 A4 = *reinterpret_cast<const float4*>(&sm[ASTR_ + bi]);
                float2 A2 = *reinterpret_cast<const float2*>(&sm[ASTR_ + bi + 4]);
                float4 B4 = *reinterpret_cast<const float4*>(&sm[2 * ASTR_ + bi]);
                float2 B2 = *reinterpret_cast<const float2*>(&sm[2 * ASTR_ + bi + 4]);
                const float fin[6]  = {F4.x, F4.y, F4.z, F4.w, F2.x, F2.y};
                const float ain[6]  = {A4.x, A4.y, A4.z, A4.w, A2.x, A2.y};
                const float bin_[6] = {B4.x, B4.y, B4.z, B4.w, B2.x, B2.y};
#pragma unroll
                for (int j = 0; j < 3; ++j) {
                    const float* wp = wcc + (i * 3 + j) * 8;
                    float4 W4 = *reinterpret_cast<const float4*>(wp);
                    float2 W2 = *reinterpret_cast<const float2*>(wp + 4);
                    const float C  = W4.x, S  = W4.y;
                    const float w0 = W4.z, w1 = W4.w;
                    const float w2 = W2.x, w3 = W2.y;
#pragma unroll
                    for (int p = 0; p < 4; ++p) {
                        const float fv  = fin [p + j];
                        const float r0v = ain [p + j];
                        const float r1v = bin_[p + j];
                        float u  = fmaf(C, r0v, S * r1v);
                        float vv = fmaf(C, r1v, -(S * r0v));
                        float g0 = fmaxf(u,  0.0f);
                        float g1 = fmaxf(vv, 0.0f);
                        float g2 = g0 - u;     // relu(-u), exact
                        float g3 = g1 - vv;    // relu(-v), exact
                        acc[p][0] = fmaf(fv * g0, w0, acc[p][0]);
                        acc[p][1] = fmaf(fv * g1, w1, acc[p][1]);
                        acc[p][2] = fmaf(fv * g2, w2, acc[p][2]);
                        acc[p][3] = fmaf(fv * g3, w3, acc[p][3]);
                    }
                }
            }
        }
    }

    // ---- epilogue: max/argmax over orientations (first-max tie-break) ----
    const float cosv[4] = {1.0f, -4.37113883e-08f, -1.0f, 1.19248806e-08f};
    const float sinv[4] = {0.0f, 1.0f, -8.74227766e-08f, -1.0f};
#pragma unroll
    for (int p = 0; p < 4; ++p) {
        int wcol = wbase + px0 + p;
        float a0 = acc[p][0], a1 = acc[p][1];
        float a2 = acc[p][2], a3 = acc[p][3];
        float best = a0; int bi = 0;
        if (a1 > best) { best = a1; bi = 1; }
        if (a2 > best) { best = a2; bi = 2; }
        if (a3 > best) { best = a3; bi = 3; }
        size_t o = ((size_t)(b * COUT_ + oc) * H_ + h) * W_ + wcol;
        out[o]              = best;
        out[o + OUTSZ_]     = cosv[bi];
        out[o + 2 * OUTSZ_] = sinv[bi];
    }
}

extern "C" void kernel_launch(void* const* d_in, const int* in_sizes, int n_in,
                              void* d_out, int out_size, void* d_ws, size_t ws_size,
                              hipStream_t stream)
{
    const float* f  = (const float*)d_in[0];
    const float* r0 = (const float*)d_in[1];
    const float* r1 = (const float*)d_in[2];
    const float* w  = (const float*)d_in[3];
    const float* wr = (const float*)d_in[4];
    float* out = (float*)d_out;
    float* tab = (float*)d_ws;    // 294912 B

    build_wtab<<<dim3(36), dim3(256), 0, stream>>>(w, wr, tab);
    orient_conv_kernel<<<dim3(B_ * H_ * 4), dim3(256), 0, stream>>>(
        f, r0, r1, tab, out);
}